// Round 11
// baseline (6120.380 us; speedup 1.0000x reference)
//
#include <hip/hip_runtime.h>
#include <hip/hip_bf16.h>

typedef __bf16 bf16x8 __attribute__((ext_vector_type(8)));
typedef __bf16 bf16x4 __attribute__((ext_vector_type(4)));
typedef float  f32x4  __attribute__((ext_vector_type(4)));
typedef unsigned int u32;
typedef unsigned long long u64;

// ---- inline-asm MFMA with B operand in AGPR (proven R7) ------------------
static __device__ __forceinline__ void mfma_z(f32x4& d, bf16x8 a, const f32x4& b) {
    asm("v_mfma_f32_16x16x32_bf16 %0, %1, %2, 0"
        : "=&v"(d) : "v"(a), "a"(b));
}
static __device__ __forceinline__ void mfma_a(f32x4& d, bf16x8 a, const f32x4& b) {
    asm("v_mfma_f32_16x16x32_bf16 %0, %1, %2, %0"
        : "+v"(d) : "v"(a), "a"(b));
}
#define ACC_GUARD(e, o) asm volatile("s_nop 7\n\ts_nop 7" : "+v"(e), "+v"(o))

static __device__ __forceinline__ f32x4 mfma16(bf16x8 a, bf16x8 b, f32x4 c) {
    return __builtin_amdgcn_mfma_f32_16x16x32_bf16(a, b, c, 0, 0, 0);
}

// ---- agent-scope exchange primitives (all LLC; no scope assumptions) -----
static __device__ __forceinline__ bf16x8 ld_frag(const __bf16* src) {
    u64 lo = __hip_atomic_load((const u64*)src,       __ATOMIC_RELAXED, __HIP_MEMORY_SCOPE_AGENT);
    u64 hi = __hip_atomic_load((const u64*)(src + 4), __ATOMIC_RELAXED, __HIP_MEMORY_SCOPE_AGENT);
    union { u64 q[2]; bf16x8 v; } u; u.q[0] = lo; u.q[1] = hi; return u.v;
}
// Bounded spin + give-up latch: if a poll ever times out (~0.5 s), the WG
// stops polling for the rest of the kernel and free-runs to completion.
// Protocol failure => fast absmax FAIL, never a container-killing hang.
// Worst-case kernel time under total failure: ~1 s.
static __device__ __forceinline__ void poll_flags(const u32* flags, u32 tgt,
                                                  int lane, u32& alive) {
    if (!alive) return;
    for (u32 it = 0; it < (1u << 22); ++it) {
        u32 v = __hip_atomic_load(&flags[lane & 7], __ATOMIC_RELAXED, __HIP_MEMORY_SCOPE_AGENT);
        if (__all((int)(v >= tgt))) return;
        __builtin_amdgcn_s_sleep(1);
    }
    alive = 0;
}

#define TLEN 512
#define IDIM 128
#define FDIM 512
#define MDIM 512
#define ODIM 128
#define BC   16
#define NGRP 16
#define NCU  8
#define PSTR 520
#define XSTR 136

#define WS_WI   0
#define WS_W2F  (WS_WI  + FDIM*IDIM*2)
#define WS_W2M  (WS_W2F + FDIM*MDIM*2)
#define WS_WF2  (WS_W2M + MDIM*MDIM*2)
#define WS_WO   (WS_WF2 + MDIM*FDIM*2)
#define WS_B1   (WS_WO  + ODIM*MDIM*2)
#define WS_B23  (WS_B1  + FDIM*4)
#define WS_CTR  (WS_B23 + MDIM*4)
#define WS_FBUF (WS_CTR + NGRP*64*4)
#define WS_MBUF (WS_FBUF + NGRP*BC*FDIM*2)

#define N_WI  (FDIM*IDIM)
#define N_W2F (FDIM*MDIM)
#define N_W2M (MDIM*MDIM)
#define N_WF2 (MDIM*FDIM)
#define N_WO  (ODIM*MDIM)
#define N_MBI (NGRP*BC*MDIM)

__global__ __launch_bounds__(256) void lmn_prep(
    const float* __restrict__ Wi2f, const float* __restrict__ Wm2f,
    const float* __restrict__ Wm2m, const float* __restrict__ Wf2m,
    const float* __restrict__ Wout, const float* __restrict__ m0,
    const float* __restrict__ bi2f, const float* __restrict__ bm2f,
    const float* __restrict__ bf2m, const float* __restrict__ bm2m,
    __bf16* __restrict__ WI, __bf16* __restrict__ W2F, __bf16* __restrict__ W2M,
    __bf16* __restrict__ WF2, __bf16* __restrict__ WO,
    float* __restrict__ b1, float* __restrict__ b23,
    u32* __restrict__ ctrs, __bf16* __restrict__ mbuf)
{
    int i = blockIdx.x * 256 + threadIdx.x;
    if (i < N_WI)  { WI[i]  = (__bf16)Wi2f[i]; return; }  i -= N_WI;
    if (i < N_W2F) { W2F[i] = (__bf16)Wm2f[i]; return; }  i -= N_W2F;
    if (i < N_W2M) { W2M[i] = (__bf16)Wm2m[i]; return; }  i -= N_W2M;
    if (i < N_WF2) { WF2[i] = (__bf16)Wf2m[i]; return; }  i -= N_WF2;
    if (i < N_WO)  { WO[i]  = (__bf16)Wout[i]; return; }  i -= N_WO;
    if (i < FDIM)  { b1[i]  = bi2f[i] + bm2f[i]; return; } i -= FDIM;
    if (i < MDIM)  { b23[i] = bf2m[i] + bm2m[i]; return; } i -= MDIM;
    if (i < NGRP * 64) { ctrs[i] = 0u; return; }           i -= NGRP * 64;
    if (i < N_MBI) {
        int g = i >> 13, rc = i & 8191;           // BC*MDIM = 8192
        int r = rc >> 9, c = rc & 511;
        mbuf[i] = (__bf16)m0[(size_t)(g * BC + r) * MDIM + c];
    }
}

// ---------------------------------------------------------------------------
// R7 compute core; exchange protocol v2: per-WG FLAG STORES (monotonic, no
// RMW), per-wave autonomous flag polls, and peer k-fragments loaded DIRECTLY
// from the exchange buffers into MFMA A-operands (no gather->LDS->barrier).
// 4 barriers/step (was 8). Overwrite gating is inductive: flagX(t) of a WG
// certifies all its epoch-t reads are done; every epoch-t overwrite happens
// after observing all peers' flagX(t).  mlds/flds hold only OWN 64 cols.
// ---------------------------------------------------------------------------
__global__ __launch_bounds__(512, 2) void lmn_scan(
    const float* __restrict__ x, const float* __restrict__ m0,
    const __bf16* __restrict__ WI, const __bf16* __restrict__ W2F,
    const __bf16* __restrict__ W2M, const __bf16* __restrict__ WF2,
    const __bf16* __restrict__ WO,
    const float* __restrict__ b1, const float* __restrict__ b23,
    const float* __restrict__ bout,
    u32* __restrict__ ctrs, __bf16* __restrict__ fbuf_all,
    __bf16* __restrict__ mbuf_all, float* __restrict__ out)
{
    __shared__ __bf16 mlds[BC][PSTR];
    __shared__ __bf16 flds[BC][PSTR];
    __shared__ __bf16 xlds[2][BC][XSTR];

    const int tid  = threadIdx.x;
    const int lane = tid & 63;
    const int w    = tid >> 6;
    const int wq   = w & 3;
    const int l15  = lane & 15;
    const int l4   = lane >> 4;
    const int koff = 8 * l4;
    const bool isG1 = (w < 4);

    const int b = blockIdx.x;
    const int g = b & 15;
    const int p = b >> 4;
    const int row0 = g * BC;

    u32*    ctr   = ctrs + g * 64;
    u32*    flagA = ctr + 16;               // 8 words
    u32*    flagB = ctr + 24;               // 8 words
    __bf16* fbuf  = fbuf_all + (size_t)g * BC * FDIM;
    __bf16* mbuf  = mbuf_all + (size_t)g * BC * MDIM;

    const int c0 = 64 * p + 16 * wq + l15;
    u32 alive = 1;

    // ---- resident weights -> AGPRs (32 frags = 128 AGPR per lane) ----
    f32x4 wA[16], wB[16];
    {
        const __bf16* rA = (isG1 ? W2F : W2M) + (size_t)c0 * MDIM;
        #pragma unroll
        for (int j = 0; j < 16; ++j)
            wA[j] = *(const f32x4*)&rA[((2 * p + j) & 15) * 32 + koff];
        if (isG1) {
            const __bf16* rB = WI + (size_t)c0 * IDIM;
            #pragma unroll
            for (int j = 0; j < 4; ++j) wB[j] = *(const f32x4*)&rB[j * 32 + koff];
            #pragma unroll
            for (int j = 4; j < 16; ++j) wB[j] = f32x4{0, 0, 0, 0};
        } else {
            const __bf16* rB = WF2 + (size_t)c0 * FDIM;
            #pragma unroll
            for (int j = 0; j < 16; ++j)
                wB[j] = *(const f32x4*)&rB[((2 * p + j) & 15) * 32 + koff];
        }
        #pragma unroll
        for (int j = 0; j < 16; ++j)
            asm volatile("" : "+a"(wA[j]), "+a"(wB[j]));
    }
    const float br = isG1 ? b1[c0] : b23[c0];

    // ---- init: own m0 cols -> mlds, x[0] -> xlds[0] ----
    if (tid < 256) {
        int r = tid >> 4, c4 = (tid & 15) << 2;
        float4 v = *(const float4*)&m0[(size_t)(row0 + r) * MDIM + 64 * p + c4];
        *(bf16x4*)&mlds[r][64 * p + c4] =
            bf16x4{(__bf16)v.x, (__bf16)v.y, (__bf16)v.z, (__bf16)v.w};
    }
    if (tid < 256) {
        int rr = tid >> 4, c8 = (tid & 15) << 3;
        const float* xs = &x[(size_t)(row0 + rr) * TLEN * IDIM + c8];
        float4 v0 = ((const float4*)xs)[0], v1 = ((const float4*)xs)[1];
        *(bf16x8*)&xlds[0][rr][c8] =
            bf16x8{(__bf16)v0.x, (__bf16)v0.y, (__bf16)v0.z, (__bf16)v0.w,
                   (__bf16)v1.x, (__bf16)v1.y, (__bf16)v1.z, (__bf16)v1.w};
    }
    __syncthreads();

    for (int t = 0; t < TLEN; ++t) {
        // ================= A-phase =================
        // own-block + x MFMAs (no peer dependency)
        f32x4 accE, accO;
        {
            bf16x8 am0 = *(const bf16x8*)&mlds[l15][((2 * p + 0) & 15) * 32 + koff];
            bf16x8 am1 = *(const bf16x8*)&mlds[l15][((2 * p + 1) & 15) * 32 + koff];
            if (isG1) {
                const __bf16 (*xc)[XSTR] = xlds[t & 1];
                bf16x8 ax0 = *(const bf16x8*)&xc[l15][0 * 32 + koff];
                bf16x8 ax1 = *(const bf16x8*)&xc[l15][1 * 32 + koff];
                bf16x8 ax2 = *(const bf16x8*)&xc[l15][2 * 32 + koff];
                bf16x8 ax3 = *(const bf16x8*)&xc[l15][3 * 32 + koff];
                mfma_z(accE, ax0, wB[0]);  mfma_z(accO, ax1, wB[1]);
                mfma_a(accE, ax2, wB[2]);  mfma_a(accO, ax3, wB[3]);
                mfma_a(accE, am0, wA[0]);  mfma_a(accO, am1, wA[1]);
            } else {
                mfma_z(accE, am0, wA[0]);  mfma_z(accO, am1, wA[1]);
            }
        }
        // wait for peers' m_t, stream their frags straight into MFMA
        poll_flags(flagB, 2u * (u32)t, lane, alive);
        #pragma unroll
        for (int j = 2; j < 16; ++j) {
            int kk = (2 * p + j) & 15;
            bf16x8 am = ld_frag(&mbuf[(size_t)l15 * MDIM + kk * 32 + koff]);
            if (j & 1) mfma_a(accO, am, wA[j]);
            else       mfma_a(accE, am, wA[j]);
        }
        if (isG1) {                     // f = tanh(pre + b1) -> own cols of flds
            ACC_GUARD(accE, accO);
            f32x4 fa = accE + accO;
            #pragma unroll
            for (int r = 0; r < 4; ++r)
                flds[4 * l4 + r][c0] = (__bf16)tanhf(fa[r] + br);
        }
        __syncthreads();                // S1: f-own in LDS

        if (tid < 256) {                // export f own block
            int rr = tid >> 4, c4 = (tid & 15) << 2;
            u64 v = *(const u64*)&flds[rr][64 * p + c4];
            __hip_atomic_store((u64*)&fbuf[rr * FDIM + 64 * p + c4], v,
                               __ATOMIC_RELAXED, __HIP_MEMORY_SCOPE_AGENT);
        }
        asm volatile("s_waitcnt vmcnt(0)" ::: "memory");
        __syncthreads();                // S2: exports drained
        if (tid == 0)
            __hip_atomic_store(&flagA[p], 2u * (u32)t + 1u,
                               __ATOMIC_RELAXED, __HIP_MEMORY_SCOPE_AGENT);

        // ================= B-phase =================
        if (isG1) {                     // stage x_{t+1}
            if (t + 1 < TLEN) {
                int rr = tid >> 4, c8 = (tid & 15) << 3;
                const float* xs = &x[((size_t)(row0 + rr) * TLEN + (t + 1)) * IDIM + c8];
                float4 v0 = ((const float4*)xs)[0], v1 = ((const float4*)xs)[1];
                *(bf16x8*)&xlds[(t + 1) & 1][rr][c8] =
                    bf16x8{(__bf16)v0.x, (__bf16)v0.y, (__bf16)v0.z, (__bf16)v0.w,
                           (__bf16)v1.x, (__bf16)v1.y, (__bf16)v1.z, (__bf16)v1.w};
            }
        } else {                        // m' = G2(acc) + f @ WF2 + b23
            bf16x8 af0 = *(const bf16x8*)&flds[l15][((2 * p + 0) & 15) * 32 + koff];
            bf16x8 af1 = *(const bf16x8*)&flds[l15][((2 * p + 1) & 15) * 32 + koff];
            mfma_a(accE, af0, wB[0]);
            mfma_a(accO, af1, wB[1]);
            poll_flags(flagA, 2u * (u32)t + 1u, lane, alive);
            #pragma unroll
            for (int j = 2; j < 16; ++j) {
                int kk = (2 * p + j) & 15;
                bf16x8 af = ld_frag(&fbuf[(size_t)l15 * FDIM + kk * 32 + koff]);
                if (j & 1) mfma_a(accO, af, wB[j]);
                else       mfma_a(accE, af, wB[j]);
            }
            ACC_GUARD(accE, accO);
            f32x4 ma = accE + accO;
            #pragma unroll
            for (int r = 0; r < 4; ++r)
                mlds[4 * l4 + r][c0] = (__bf16)(ma[r] + br);
        }
        __syncthreads();                // S5: m'-own in LDS

        if (tid >= 256) {               // export m' own block
            int u = tid - 256;
            int rr = u >> 4, c4 = (u & 15) << 2;
            u64 v = *(const u64*)&mlds[rr][64 * p + c4];
            __hip_atomic_store((u64*)&mbuf[rr * MDIM + 64 * p + c4], v,
                               __ATOMIC_RELAXED, __HIP_MEMORY_SCOPE_AGENT);
        }
        asm volatile("s_waitcnt vmcnt(0)" ::: "memory");
        __syncthreads();                // S6: exports drained
        if (tid == 0)
            __hip_atomic_store(&flagB[p], 2u * (u32)t + 2u,
                               __ATOMIC_RELAXED, __HIP_MEMORY_SCOPE_AGENT);
    }

    // ---- epilogue: group rep (p==0) computes out = m_T @ Wout^T + bout ----
    if (p == 0) {
        poll_flags(flagB, 2u * TLEN, lane, alive);
        for (int s = tid; s < 1792; s += 512) {   // gather peers' m_T
            int q = 1 + (s >> 8);
            int k = s & 255;
            int rr = k >> 4, c4 = (k & 15) << 2;
            u64 v = __hip_atomic_load((const u64*)&mbuf[rr * MDIM + 64 * q + c4],
                                      __ATOMIC_RELAXED, __HIP_MEMORY_SCOPE_AGENT);
            *(u64*)&mlds[rr][64 * q + c4] = v;
        }
        __syncthreads();
        const int oc = 16 * w + l15;
        const __bf16* ro = WO + (size_t)oc * MDIM;
        f32x4 oe = {0, 0, 0, 0}, oo = {0, 0, 0, 0};
        #pragma unroll
        for (int j = 0; j < 16; ++j) {
            bf16x8 am = *(const bf16x8*)&mlds[l15][j * 32 + koff];
            bf16x8 bw = *(const bf16x8*)&ro[j * 32 + koff];
            if (j & 1) oo = mfma16(am, bw, oo); else oe = mfma16(am, bw, oe);
        }
        f32x4 oa = oe + oo;
        const float bo = bout[oc];
        #pragma unroll
        for (int r = 0; r < 4; ++r)
            out[(size_t)(row0 + 4 * l4 + r) * ODIM + oc] = oa[r] + bo;
    }
}

extern "C" void kernel_launch(void* const* d_in, const int* in_sizes, int n_in,
                              void* d_out, int out_size, void* d_ws, size_t ws_size,
                              hipStream_t stream)
{
    const float* x    = (const float*)d_in[0];
    const float* m0   = (const float*)d_in[1];
    const float* Wi2f = (const float*)d_in[2];
    const float* bi2f = (const float*)d_in[3];
    const float* Wm2f = (const float*)d_in[4];
    const float* bm2f = (const float*)d_in[5];
    const float* Wf2m = (const float*)d_in[6];
    const float* bf2m = (const float*)d_in[7];
    const float* Wm2m = (const float*)d_in[8];
    const float* bm2m = (const float*)d_in[9];
    const float* Wout = (const float*)d_in[10];
    const float* bout = (const float*)d_in[11];

    char* ws = (char*)d_ws;
    __bf16* WI  = (__bf16*)(ws + WS_WI);
    __bf16* W2F = (__bf16*)(ws + WS_W2F);
    __bf16* W2M = (__bf16*)(ws + WS_W2M);
    __bf16* WF2 = (__bf16*)(ws + WS_WF2);
    __bf16* WO  = (__bf16*)(ws + WS_WO);
    float*  b1  = (float*)(ws + WS_B1);
    float*  b23 = (float*)(ws + WS_B23);
    u32*    ctr = (u32*)(ws + WS_CTR);
    __bf16* fb  = (__bf16*)(ws + WS_FBUF);
    __bf16* mb  = (__bf16*)(ws + WS_MBUF);

    const int prep_total = N_WI + N_W2F + N_W2M + N_WF2 + N_WO
                         + FDIM + MDIM + NGRP * 64 + N_MBI;
    lmn_prep<<<(prep_total + 255) / 256, 256, 0, stream>>>(
        Wi2f, Wm2f, Wm2m, Wf2m, Wout, m0, bi2f, bm2f, bf2m, bm2m,
        WI, W2F, W2M, WF2, WO, b1, b23, ctr, mb);

    lmn_scan<<<NGRP * NCU, 512, 0, stream>>>(
        x, m0, WI, W2F, W2M, WF2, WO, b1, b23, bout, ctr, fb, mb, (float*)d_out);
}

// Round 12
// 3762.272 us; speedup vs baseline: 1.6268x; 1.6268x over previous
//
#include <hip/hip_runtime.h>
#include <hip/hip_bf16.h>

typedef __bf16 bf16x8 __attribute__((ext_vector_type(8)));
typedef __bf16 bf16x4 __attribute__((ext_vector_type(4)));
typedef float  f32x4  __attribute__((ext_vector_type(4)));
typedef unsigned int u32;
typedef unsigned long long u64;

// ---- inline-asm MFMA with B operand in AGPR (proven R7) ------------------
static __device__ __forceinline__ void mfma_z(f32x4& d, bf16x8 a, const f32x4& b) {
    asm("v_mfma_f32_16x16x32_bf16 %0, %1, %2, 0"
        : "=&v"(d) : "v"(a), "a"(b));
}
static __device__ __forceinline__ void mfma_a(f32x4& d, bf16x8 a, const f32x4& b) {
    asm("v_mfma_f32_16x16x32_bf16 %0, %1, %2, %0"
        : "+v"(d) : "v"(a), "a"(b));
}
#define ACC_GUARD(e, o) asm volatile("s_nop 7\n\ts_nop 7" : "+v"(e), "+v"(o))

static __device__ __forceinline__ f32x4 mfma16(bf16x8 a, bf16x8 b, f32x4 c) {
    return __builtin_amdgcn_mfma_f32_16x16x32_bf16(a, b, c, 0, 0, 0);
}

// Bounded spin + give-up latch (protocol failure -> fast absmax FAIL, no hang)
static __device__ __forceinline__ void poll_flags(const u32* flags, u32 tgt,
                                                  int lane, u32& alive) {
    if (!alive) return;
    for (u32 it = 0; it < (1u << 20); ++it) {
        u32 v = __hip_atomic_load(&flags[lane & 7], __ATOMIC_RELAXED, __HIP_MEMORY_SCOPE_AGENT);
        if (__all((int)(v >= tgt))) return;
        __builtin_amdgcn_s_sleep(1);
    }
    alive = 0;
}

#define TLEN 512
#define IDIM 128
#define FDIM 512
#define MDIM 512
#define ODIM 128
#define BC   16
#define NGRP 16
#define NCU  8
#define PSTR 520     // mlds/plds stride (1040B = 65*16)
#define FSTR 72
#define XSTR 136

#define WS_WI   0
#define WS_W2F  (WS_WI  + FDIM*IDIM*2)
#define WS_W2M  (WS_W2F + FDIM*MDIM*2)
#define WS_WF2  (WS_W2M + MDIM*MDIM*2)
#define WS_WO   (WS_WF2 + MDIM*FDIM*2)
#define WS_B1   (WS_WO  + ODIM*MDIM*2)
#define WS_B23  (WS_B1  + FDIM*4)
#define WS_CTR  (WS_B23 + MDIM*4)
#define WS_PBUF (WS_CTR + NGRP*64*4)    // bf16 [2][NGRP][NCU][BC][MDIM] = 4 MB

#define N_WI  (FDIM*IDIM)
#define N_W2F (FDIM*MDIM)
#define N_W2M (MDIM*MDIM)
#define N_WF2 (MDIM*FDIM)
#define N_WO  (ODIM*MDIM)

__global__ __launch_bounds__(256) void lmn_prep(
    const float* __restrict__ Wi2f, const float* __restrict__ Wm2f,
    const float* __restrict__ Wm2m, const float* __restrict__ Wf2m,
    const float* __restrict__ Wout,
    const float* __restrict__ bi2f, const float* __restrict__ bm2f,
    const float* __restrict__ bf2m, const float* __restrict__ bm2m,
    __bf16* __restrict__ WI, __bf16* __restrict__ W2F, __bf16* __restrict__ W2M,
    __bf16* __restrict__ WF2, __bf16* __restrict__ WO,
    float* __restrict__ b1, float* __restrict__ b23, u32* __restrict__ ctrs)
{
    int i = blockIdx.x * 256 + threadIdx.x;
    if (i < N_WI)  { WI[i]  = (__bf16)Wi2f[i]; return; }  i -= N_WI;
    if (i < N_W2F) { W2F[i] = (__bf16)Wm2f[i]; return; }  i -= N_W2F;
    if (i < N_W2M) { W2M[i] = (__bf16)Wm2m[i]; return; }  i -= N_W2M;
    if (i < N_WF2) { WF2[i] = (__bf16)Wf2m[i]; return; }  i -= N_WF2;
    if (i < N_WO)  { WO[i]  = (__bf16)Wout[i]; return; }  i -= N_WO;
    if (i < FDIM)  { b1[i]  = bi2f[i] + bm2f[i]; return; } i -= FDIM;
    if (i < MDIM)  { b23[i] = bf2m[i] + bm2m[i]; return; } i -= MDIM;
    if (i < NGRP * 64) { ctrs[i] = 0u; return; }
}

// ---------------------------------------------------------------------------
// ONE exchange event per step via K-split m' partials:
//   waves 0-3 (G1): f_own = tanh(x@WI_own + m@W2F_own + b1_own) -> flds
//   waves 4-7:      partial_p = m[:,ownK]@W2M[:,ownK]^T + f_own@WF2[:,ownK]^T
//                   (16 x 512, K=64; f slice needed == f_own, so f is NEVER
//                   exchanged). -> plds -> pbuf[t&1] (coalesced 16 KB export)
//   flag[p]=t+1 -> poll all>=t+1 -> ALL WGs gather 8 partials (128 KB,
//   coalesced) and redundantly reduce m_{t+1} = sum + b23 -> mlds (bf16).
// Parity double-buffer; flag(t+1) certifies gather(t-1) done (program order),
// overwrite of epoch t (at t+2, same parity) gated by flags >= t+2.
// Weights AGPR-resident (32 frags = 128 AGPR). R11-validated flag protocol;
// R11's lesson applied: all bulk data moves are coalesced line-granular.
// ---------------------------------------------------------------------------
__global__ __launch_bounds__(512, 2) void lmn_scan(
    const float* __restrict__ x, const float* __restrict__ m0,
    const __bf16* __restrict__ WI, const __bf16* __restrict__ W2F,
    const __bf16* __restrict__ W2M, const __bf16* __restrict__ WF2,
    const __bf16* __restrict__ WO,
    const float* __restrict__ b1, const float* __restrict__ b23,
    const float* __restrict__ bout,
    u32* __restrict__ ctrs, __bf16* __restrict__ pbuf,
    float* __restrict__ out)
{
    __shared__ __bf16 mlds[BC][PSTR];
    __shared__ __bf16 flds[BC][FSTR];
    __shared__ __bf16 plds[BC][PSTR];
    __shared__ __bf16 xlds[2][BC][XSTR];

    const int tid  = threadIdx.x;
    const int lane = tid & 63;
    const int w    = tid >> 6;
    const int wq   = w & 3;
    const int l15  = lane & 15;
    const int l4   = lane >> 4;
    const int koff = 8 * l4;
    const bool isG1 = (w < 4);

    const int b = blockIdx.x;
    const int g = b & 15;
    const int p = b >> 4;
    const int row0 = g * BC;

    u32* flags = ctrs + g * 64 + 16;
    u32  alive = 1;

    // ---- resident weights -> AGPRs (32 frags = 128 AGPR) ----
    f32x4 wgt[32];
    if (isG1) {
        const int fc = 64 * p + 16 * wq + l15;          // own f col
        const __bf16* rA = W2F + (size_t)fc * MDIM;
        #pragma unroll
        for (int j = 0; j < 16; ++j) wgt[j] = *(const f32x4*)&rA[j * 32 + koff];
        const __bf16* rX = WI + (size_t)fc * IDIM;
        #pragma unroll
        for (int j = 0; j < 4; ++j) wgt[16 + j] = *(const f32x4*)&rX[j * 32 + koff];
        #pragma unroll
        for (int j = 20; j < 32; ++j) wgt[j] = f32x4{0, 0, 0, 0};
    } else {
        const int nb = 128 * wq;                        // wave's 128 m'-cols
        #pragma unroll
        for (int nt = 0; nt < 8; ++nt)
            #pragma unroll
            for (int ki = 0; ki < 2; ++ki) {
                wgt[nt * 2 + ki] = *(const f32x4*)
                    &W2M[(size_t)(nb + nt * 16 + l15) * MDIM + 64 * p + ki * 32 + koff];
                wgt[16 + nt * 2 + ki] = *(const f32x4*)
                    &WF2[(size_t)(nb + nt * 16 + l15) * FDIM + 64 * p + ki * 32 + koff];
            }
    }
    #pragma unroll
    for (int j = 0; j < 32; ++j) asm volatile("" : "+a"(wgt[j]));

    const float b1r = isG1 ? b1[64 * p + 16 * wq + l15] : 0.f;

    // ---- init: full m0 -> mlds, x[0] -> xlds[0] ----
    for (int u = tid; u < BC * MDIM / 4; u += 512) {
        int r = u >> 7, c = (u & 127) * 4;
        float4 v = *(const float4*)&m0[(size_t)(row0 + r) * MDIM + c];
        *(bf16x4*)&mlds[r][c] = bf16x4{(__bf16)v.x, (__bf16)v.y, (__bf16)v.z, (__bf16)v.w};
    }
    if (tid < 256) {
        int rr = tid >> 4, c8 = (tid & 15) << 3;
        const float* xs = &x[(size_t)(row0 + rr) * TLEN * IDIM + c8];
        float4 v0 = ((const float4*)xs)[0], v1 = ((const float4*)xs)[1];
        *(bf16x8*)&xlds[0][rr][c8] =
            bf16x8{(__bf16)v0.x, (__bf16)v0.y, (__bf16)v0.z, (__bf16)v0.w,
                   (__bf16)v1.x, (__bf16)v1.y, (__bf16)v1.z, (__bf16)v1.w};
    }
    __syncthreads();

    const int grow = tid >> 5;              // export/gather row 0..15
    const int gcb  = (tid & 31) * 16;       // export/gather col base (16 elems)

    f32x4 pa[8];                            // partial accs (waves 4-7)

    for (int t = 0; t < TLEN; ++t) {
        const size_t parbase = (size_t)((t & 1) * NGRP + g) * NCU * (BC * MDIM);

        // ---- phase 1: G1 (f) || partM ----
        if (isG1) {
            f32x4 accE, accO;
            const __bf16 (*xc)[XSTR] = xlds[t & 1];
            bf16x8 ax0 = *(const bf16x8*)&xc[l15][0 * 32 + koff];
            bf16x8 ax1 = *(const bf16x8*)&xc[l15][1 * 32 + koff];
            bf16x8 ax2 = *(const bf16x8*)&xc[l15][2 * 32 + koff];
            bf16x8 ax3 = *(const bf16x8*)&xc[l15][3 * 32 + koff];
            mfma_z(accE, ax0, wgt[16]);  mfma_z(accO, ax1, wgt[17]);
            mfma_a(accE, ax2, wgt[18]);  mfma_a(accO, ax3, wgt[19]);
            #pragma unroll
            for (int j = 0; j < 16; ++j) {
                bf16x8 am = *(const bf16x8*)&mlds[l15][j * 32 + koff];
                if (j & 1) mfma_a(accO, am, wgt[j]);
                else       mfma_a(accE, am, wgt[j]);
            }
            ACC_GUARD(accE, accO);
            f32x4 fa = accE + accO;
            #pragma unroll
            for (int r = 0; r < 4; ++r)
                flds[4 * l4 + r][16 * wq + l15] = (__bf16)tanhf(fa[r] + b1r);
        } else {
            bf16x8 am0 = *(const bf16x8*)&mlds[l15][64 * p + koff];
            bf16x8 am1 = *(const bf16x8*)&mlds[l15][64 * p + 32 + koff];
            #pragma unroll
            for (int nt = 0; nt < 8; ++nt) {
                mfma_z(pa[nt], am0, wgt[nt * 2]);
                mfma_a(pa[nt], am1, wgt[nt * 2 + 1]);
            }
        }
        __syncthreads();                    // S1: f_own in flds

        // ---- phase 2: partF -> plds  || x_{t+1} staging ----
        if (isG1) {
            if (t + 1 < TLEN) {
                int rr = tid >> 4, c8 = (tid & 15) << 3;
                const float* xs = &x[((size_t)(row0 + rr) * TLEN + (t + 1)) * IDIM + c8];
                float4 v0 = ((const float4*)xs)[0], v1 = ((const float4*)xs)[1];
                *(bf16x8*)&xlds[(t + 1) & 1][rr][c8] =
                    bf16x8{(__bf16)v0.x, (__bf16)v0.y, (__bf16)v0.z, (__bf16)v0.w,
                           (__bf16)v1.x, (__bf16)v1.y, (__bf16)v1.z, (__bf16)v1.w};
            }
        } else {
            bf16x8 af0 = *(const bf16x8*)&flds[l15][koff];
            bf16x8 af1 = *(const bf16x8*)&flds[l15][32 + koff];
            #pragma unroll
            for (int nt = 0; nt < 8; ++nt) {
                mfma_a(pa[nt], af0, wgt[16 + nt * 2]);
                mfma_a(pa[nt], af1, wgt[16 + nt * 2 + 1]);
            }
            ACC_GUARD(pa[0], pa[1]);  ACC_GUARD(pa[2], pa[3]);
            ACC_GUARD(pa[4], pa[5]);  ACC_GUARD(pa[6], pa[7]);
            const int nb = 128 * wq;
            #pragma unroll
            for (int nt = 0; nt < 8; ++nt)
                #pragma unroll
                for (int r = 0; r < 4; ++r)
                    plds[4 * l4 + r][nb + nt * 16 + l15] = (__bf16)pa[nt][r];
        }
        __syncthreads();                    // S2: plds = partial_p

        // ---- export partial (coalesced 32B/thread) ----
        {
            __bf16* dst = pbuf + parbase + (size_t)p * (BC * MDIM) + grow * MDIM + gcb;
            const __bf16* s = &plds[grow][gcb];
            u64 q0 = *(const u64*)(s);      u64 q1 = *(const u64*)(s + 4);
            u64 q2 = *(const u64*)(s + 8);  u64 q3 = *(const u64*)(s + 12);
            __hip_atomic_store((u64*)(dst),      q0, __ATOMIC_RELAXED, __HIP_MEMORY_SCOPE_AGENT);
            __hip_atomic_store((u64*)(dst + 4),  q1, __ATOMIC_RELAXED, __HIP_MEMORY_SCOPE_AGENT);
            __hip_atomic_store((u64*)(dst + 8),  q2, __ATOMIC_RELAXED, __HIP_MEMORY_SCOPE_AGENT);
            __hip_atomic_store((u64*)(dst + 12), q3, __ATOMIC_RELAXED, __HIP_MEMORY_SCOPE_AGENT);
        }
        asm volatile("s_waitcnt vmcnt(0)" ::: "memory");
        __syncthreads();                    // S3: exports drained
        if (tid == 0)
            __hip_atomic_store(&flags[p], (u32)t + 1u,
                               __ATOMIC_RELAXED, __HIP_MEMORY_SCOPE_AGENT);

        // ---- poll + gather 8 partials (coalesced) + reduce -> mlds ----
        poll_flags(flags, (u32)t + 1u, lane, alive);
        {
            float4 bv0 = *(const float4*)&b23[gcb];
            float4 bv1 = *(const float4*)&b23[gcb + 4];
            float4 bv2 = *(const float4*)&b23[gcb + 8];
            float4 bv3 = *(const float4*)&b23[gcb + 12];
            float s[16] = {bv0.x, bv0.y, bv0.z, bv0.w, bv1.x, bv1.y, bv1.z, bv1.w,
                           bv2.x, bv2.y, bv2.z, bv2.w, bv3.x, bv3.y, bv3.z, bv3.w};
            #pragma unroll
            for (int q = 0; q < 8; ++q) {
                const __bf16* src = pbuf + parbase + (size_t)q * (BC * MDIM)
                                  + grow * MDIM + gcb;
                u64 q0 = __hip_atomic_load((const u64*)(src),      __ATOMIC_RELAXED, __HIP_MEMORY_SCOPE_AGENT);
                u64 q1 = __hip_atomic_load((const u64*)(src + 4),  __ATOMIC_RELAXED, __HIP_MEMORY_SCOPE_AGENT);
                u64 q2 = __hip_atomic_load((const u64*)(src + 8),  __ATOMIC_RELAXED, __HIP_MEMORY_SCOPE_AGENT);
                u64 q3 = __hip_atomic_load((const u64*)(src + 12), __ATOMIC_RELAXED, __HIP_MEMORY_SCOPE_AGENT);
                union { u64 q[4]; __bf16 h[16]; } u;
                u.q[0] = q0; u.q[1] = q1; u.q[2] = q2; u.q[3] = q3;
                #pragma unroll
                for (int j = 0; j < 16; ++j) s[j] += (float)u.h[j];
            }
            bf16x8 o0, o1;
            #pragma unroll
            for (int j = 0; j < 8; ++j) { o0[j] = (__bf16)s[j]; o1[j] = (__bf16)s[8 + j]; }
            *(bf16x8*)&mlds[grow][gcb]     = o0;
            *(bf16x8*)&mlds[grow][gcb + 8] = o1;
        }
        __syncthreads();                    // S4: mlds = m_{t+1}
    }

    // ---- epilogue: p==0 computes out = m_T @ Wout^T + bout (mlds is full) --
    if (p == 0) {
        const int oc = 16 * w + l15;
        const __bf16* ro = WO + (size_t)oc * MDIM;
        f32x4 oe = {0, 0, 0, 0}, oo = {0, 0, 0, 0};
        #pragma unroll
        for (int j = 0; j < 16; ++j) {
            bf16x8 am = *(const bf16x8*)&mlds[l15][j * 32 + koff];
            bf16x8 bw = *(const bf16x8*)&ro[j * 32 + koff];
            if (j & 1) oo = mfma16(am, bw, oo); else oe = mfma16(am, bw, oe);
        }
        f32x4 oa = oe + oo;
        const float bo = bout[oc];
        #pragma unroll
        for (int r = 0; r < 4; ++r)
            out[(size_t)(row0 + 4 * l4 + r) * ODIM + oc] = oa[r] + bo;
    }
}

extern "C" void kernel_launch(void* const* d_in, const int* in_sizes, int n_in,
                              void* d_out, int out_size, void* d_ws, size_t ws_size,
                              hipStream_t stream)
{
    const float* x    = (const float*)d_in[0];
    const float* m0   = (const float*)d_in[1];
    const float* Wi2f = (const float*)d_in[2];
    const float* bi2f = (const float*)d_in[3];
    const float* Wm2f = (const float*)d_in[4];
    const float* bm2f = (const float*)d_in[5];
    const float* Wf2m = (const float*)d_in[6];
    const float* bf2m = (const float*)d_in[7];
    const float* Wm2m = (const float*)d_in[8];
    const float* bm2m = (const float*)d_in[9];
    const float* Wout = (const float*)d_in[10];
    const float* bout = (const float*)d_in[11];

    char* ws = (char*)d_ws;
    __bf16* WI  = (__bf16*)(ws + WS_WI);
    __bf16* W2F = (__bf16*)(ws + WS_W2F);
    __bf16* W2M = (__bf16*)(ws + WS_W2M);
    __bf16* WF2 = (__bf16*)(ws + WS_WF2);
    __bf16* WO  = (__bf16*)(ws + WS_WO);
    float*  b1  = (float*)(ws + WS_B1);
    float*  b23 = (float*)(ws + WS_B23);
    u32*    ctr = (u32*)(ws + WS_CTR);
    __bf16* pb  = (__bf16*)(ws + WS_PBUF);

    const int prep_total = N_WI + N_W2F + N_W2M + N_WF2 + N_WO + FDIM + MDIM + NGRP * 64;
    lmn_prep<<<(prep_total + 255) / 256, 256, 0, stream>>>(
        Wi2f, Wm2f, Wm2m, Wf2m, Wout, bi2f, bm2f, bf2m, bm2m,
        WI, W2F, W2M, WF2, WO, b1, b23, ctr);

    lmn_scan<<<NGRP * NCU, 512, 0, stream>>>(
        x, m0, WI, W2F, W2M, WF2, WO, b1, b23, bout, ctr, pb, (float*)d_out);
}

// Round 13
// 1880.749 us; speedup vs baseline: 3.2542x; 2.0004x over previous
//
#include <hip/hip_runtime.h>
#include <hip/hip_bf16.h>

typedef __bf16 bf16x8 __attribute__((ext_vector_type(8)));
typedef __bf16 bf16x4 __attribute__((ext_vector_type(4)));
typedef float  f32x4  __attribute__((ext_vector_type(4)));
typedef unsigned int u32;
typedef unsigned long long u64;

// ---- inline-asm MFMA with B operand in AGPR (proven R7/R12) --------------
static __device__ __forceinline__ void mfma_z(f32x4& d, bf16x8 a, const f32x4& b) {
    asm("v_mfma_f32_16x16x32_bf16 %0, %1, %2, 0"
        : "=&v"(d) : "v"(a), "a"(b));
}
static __device__ __forceinline__ void mfma_a(f32x4& d, bf16x8 a, const f32x4& b) {
    asm("v_mfma_f32_16x16x32_bf16 %0, %1, %2, %0"
        : "+v"(d) : "v"(a), "a"(b));
}
#define ACC_GUARD(e, o) asm volatile("s_nop 7\n\ts_nop 7" : "+v"(e), "+v"(o))

static __device__ __forceinline__ f32x4 mfma16(bf16x8 a, bf16x8 b, f32x4 c) {
    return __builtin_amdgcn_mfma_f32_16x16x32_bf16(a, b, c, 0, 0, 0);
}

// Bounded spin + give-up latch (protocol failure -> fast absmax FAIL, no hang)
static __device__ __forceinline__ void poll_flags(const u32* flags, u32 tgt,
                                                  int lane, u32& alive) {
    if (!alive) return;
    for (u32 it = 0; it < (1u << 20); ++it) {
        u32 v = __hip_atomic_load(&flags[lane & 7], __ATOMIC_RELAXED, __HIP_MEMORY_SCOPE_AGENT);
        if (__all((int)(v >= tgt))) return;
        __builtin_amdgcn_s_sleep(1);
    }
    alive = 0;
}

#define TLEN 512
#define IDIM 128
#define FDIM 512
#define MDIM 512
#define ODIM 128
#define BC   16
#define NGRP 16
#define NCU  8
#define PSTR 520
#define XSTR 136

// ---- ws byte offsets ----
#define WS_WI   0                               // bf16 [512][128]
#define WS_W2F  (WS_WI  + FDIM*IDIM*2)          // bf16 [512][512] (Wm2f)
#define WS_W2M  (WS_W2F + FDIM*MDIM*2)          // bf16 [512][512] (Wm2m)
#define WS_WF2  (WS_W2M + MDIM*MDIM*2)          // bf16 [512][512] (Wf2m)
#define WS_WO   (WS_WF2 + MDIM*FDIM*2)          // bf16 [128][512]
#define WS_C    (WS_WO  + ODIM*MDIM*2)          // bf16 [512][512] = Wm2f@Wf2m
#define WS_D    (WS_C   + FDIM*FDIM*2)          // bf16 [512][512] = Wm2m@Wf2m
#define WS_B1   (WS_D   + MDIM*FDIM*2)          // f32 512
#define WS_B23  (WS_B1  + FDIM*4)               // f32 512
#define WS_CB   (WS_B23 + MDIM*4)               // f32 512: b1 + Wm2f@b23
#define WS_CU   (WS_CB  + FDIM*4)               // f32 512: Wm2m@b23
#define WS_FLG  (WS_CU  + MDIM*4)               // u32 [NGRP][64]
#define WS_BUF  (WS_FLG + NGRP*64*4)            // bf16 [2][NGRP][2][16][512] = 1MB

#define N_WI  (FDIM*IDIM)
#define N_W2F (FDIM*MDIM)
#define N_W2M (MDIM*MDIM)
#define N_WF2 (MDIM*FDIM)
#define N_WO  (ODIM*MDIM)

__global__ __launch_bounds__(256) void lmn_prep1(
    const float* __restrict__ Wi2f, const float* __restrict__ Wm2f,
    const float* __restrict__ Wm2m, const float* __restrict__ Wf2m,
    const float* __restrict__ Wout,
    const float* __restrict__ bi2f, const float* __restrict__ bm2f,
    const float* __restrict__ bf2m, const float* __restrict__ bm2m,
    __bf16* __restrict__ WI, __bf16* __restrict__ W2F, __bf16* __restrict__ W2M,
    __bf16* __restrict__ WF2, __bf16* __restrict__ WO,
    float* __restrict__ b1, float* __restrict__ b23, u32* __restrict__ flags)
{
    int i = blockIdx.x * 256 + threadIdx.x;
    if (i < N_WI)  { WI[i]  = (__bf16)Wi2f[i]; return; }  i -= N_WI;
    if (i < N_W2F) { W2F[i] = (__bf16)Wm2f[i]; return; }  i -= N_W2F;
    if (i < N_W2M) { W2M[i] = (__bf16)Wm2m[i]; return; }  i -= N_W2M;
    if (i < N_WF2) { WF2[i] = (__bf16)Wf2m[i]; return; }  i -= N_WF2;
    if (i < N_WO)  { WO[i]  = (__bf16)Wout[i]; return; }  i -= N_WO;
    if (i < FDIM)  { b1[i]  = bi2f[i] + bm2f[i]; return; } i -= FDIM;
    if (i < MDIM)  { b23[i] = bf2m[i] + bm2m[i]; return; } i -= MDIM;
    if (i < NGRP * 64) { flags[i] = 0u; return; }
}

// Composites: C = Wm2f@Wf2m, D = Wm2m@Wf2m (bf16), cb = b1 + Wm2f@b23,
// cu = Wm2m@b23. Blocks 0..2047: GEMM rows (coalesced over k); 2048..2051: biases.
__global__ __launch_bounds__(256) void lmn_prep2(
    const float* __restrict__ Wm2f, const float* __restrict__ Wm2m,
    const float* __restrict__ Wf2m,
    const float* __restrict__ b1, const float* __restrict__ b23,
    __bf16* __restrict__ C, __bf16* __restrict__ D,
    float* __restrict__ cb, float* __restrict__ cu)
{
    int bb = blockIdx.x;
    if (bb < 2048) {
        int row = bb >> 1;                       // 0..1023
        int k   = (bb & 1) * 256 + threadIdx.x;  // 0..511
        const float* A = (row < 512) ? Wm2f : Wm2m;
        int r = row & 511;
        float acc = 0.f;
        for (int j = 0; j < 512; ++j)
            acc += A[(size_t)r * 512 + j] * Wf2m[(size_t)j * 512 + k];
        if (row < 512) C[(size_t)r * 512 + k] = (__bf16)acc;
        else           D[(size_t)r * 512 + k] = (__bf16)acc;
        return;
    }
    int idx = (bb - 2048) * 256 + threadIdx.x;   // 0..1023
    if (idx < 512) {
        float acc = b1[idx];
        for (int j = 0; j < 512; ++j) acc += Wm2f[(size_t)idx * 512 + j] * b23[j];
        cb[idx] = acc;
    } else {
        int r = idx - 512;
        float acc = 0.f;
        for (int j = 0; j < 512; ++j) acc += Wm2m[(size_t)r * 512 + j] * b23[j];
        cu[r] = acc;
    }
}

// ---------------------------------------------------------------------------
// State-transformed scan: state (u,s) with u=m@W2M^T, s=m@W2F^T.
//   f_t  = tanh(x_t@WI^T + s_t + b1/cb)      [elementwise — NO exchange]
//   s' = u@W2F^T + f@C^T (+cs), u' = u@W2M^T + f@D^T (+cu)
// ONE exchange event/step: (u_own, f_own) -> buf[t&1] (4 KB/WG coalesced),
// flag, per-wave poll, coalesced 32 KB gather -> ulds/flds, MFMA chains.
// Roles: waves 0-3 own s/f cols (W2F+C+WI rows in AGPR, 144), waves 4-7 own
// u cols (W2M+D rows, 128 AGPR). Overwrite gating inductive as R12 (parity
// dbuf; flag(t+1) follows gather(t-1) in program order). m0 epilogue-free:
// prologue seeds (s0,u0)=m0@{W2F,W2M}^T; epilogue m_T = u+f@WF2^T+b23 on p==0.
// ---------------------------------------------------------------------------
__global__ __launch_bounds__(512, 2) void lmn_scan(
    const float* __restrict__ x, const float* __restrict__ m0,
    const __bf16* __restrict__ WI, const __bf16* __restrict__ W2F,
    const __bf16* __restrict__ W2M, const __bf16* __restrict__ Cm,
    const __bf16* __restrict__ Dm, const __bf16* __restrict__ WF2,
    const __bf16* __restrict__ WO,
    const float* __restrict__ b1, const float* __restrict__ cb,
    const float* __restrict__ cu, const float* __restrict__ b23,
    const float* __restrict__ bout,
    u32* __restrict__ flags_all, __bf16* __restrict__ buf,
    float* __restrict__ out)
{
    __shared__ __bf16 ulds[BC][PSTR];
    __shared__ __bf16 flds[BC][PSTR];
    __shared__ __bf16 xlds[BC][XSTR];

    const int tid  = threadIdx.x;
    const int lane = tid & 63;
    const int w    = tid >> 6;
    const int wq   = w & 3;
    const int l15  = lane & 15;
    const int l4   = lane >> 4;
    const int koff = 8 * l4;
    const bool sRole = (w < 4);

    const int b = blockIdx.x;
    const int g = b & 15;
    const int p = b >> 4;
    const int row0 = g * BC;

    u32* flags = flags_all + g * 64;
    u32  alive = 1;

    const int c0 = 64 * p + 16 * wq + l15;   // own s/f col (sRole) or u col

    // ---- resident weights -> AGPRs (36 frags = 144 AGPR max) ----
    f32x4 wgt[36];
    {
        const __bf16* rA = (sRole ? W2F : W2M) + (size_t)c0 * MDIM;
        const __bf16* rC = (sRole ? Cm  : Dm ) + (size_t)c0 * FDIM;
        #pragma unroll
        for (int j = 0; j < 16; ++j) {
            wgt[j]      = *(const f32x4*)&rA[j * 32 + koff];
            wgt[16 + j] = *(const f32x4*)&rC[j * 32 + koff];
        }
        if (sRole) {
            const __bf16* rX = WI + (size_t)c0 * IDIM;
            #pragma unroll
            for (int j = 0; j < 4; ++j) wgt[32 + j] = *(const f32x4*)&rX[j * 32 + koff];
        } else {
            #pragma unroll
            for (int j = 32; j < 36; ++j) wgt[j] = f32x4{0, 0, 0, 0};
        }
        #pragma unroll
        for (int j = 0; j < 36; ++j) asm volatile("" : "+a"(wgt[j]));
    }
    const float b1r = sRole ? b1[c0] : 0.f;
    const float cbr = sRole ? cb[c0] : 0.f;
    const float cur = sRole ? 0.f    : cu[c0];

    // ---- prologue: m0 -> ulds, x0 -> xlds; seed accs ----
    #pragma unroll
    for (int i = 0; i < 2; ++i) {                 // 1024 8-elem chunks of m0
        int c = tid + 512 * i;
        int row = c >> 6, col8 = (c & 63) << 3;
        const float* ms = &m0[(size_t)(row0 + row) * MDIM + col8];
        float4 v0 = ((const float4*)ms)[0], v1 = ((const float4*)ms)[1];
        *(bf16x8*)&ulds[row][col8] =
            bf16x8{(__bf16)v0.x, (__bf16)v0.y, (__bf16)v0.z, (__bf16)v0.w,
                   (__bf16)v1.x, (__bf16)v1.y, (__bf16)v1.z, (__bf16)v1.w};
    }
    if (tid < 256) {
        int rr = tid >> 4, c8 = (tid & 15) << 3;
        const float* xs = &x[(size_t)(row0 + rr) * TLEN * IDIM + c8];
        float4 v0 = ((const float4*)xs)[0], v1 = ((const float4*)xs)[1];
        *(bf16x8*)&xlds[rr][c8] =
            bf16x8{(__bf16)v0.x, (__bf16)v0.y, (__bf16)v0.z, (__bf16)v0.w,
                   (__bf16)v1.x, (__bf16)v1.y, (__bf16)v1.z, (__bf16)v1.w};
    }
    __syncthreads();

    f32x4 accE, accO;                             // s-acc (sRole) / u-acc
    {
        bf16x8 a0 = *(const bf16x8*)&ulds[l15][0 * 32 + koff];
        bf16x8 a1 = *(const bf16x8*)&ulds[l15][1 * 32 + koff];
        mfma_z(accE, a0, wgt[0]);  mfma_z(accO, a1, wgt[1]);
        #pragma unroll
        for (int j = 2; j < 16; ++j) {
            bf16x8 am = *(const bf16x8*)&ulds[l15][j * 32 + koff];
            if (j & 1) mfma_a(accO, am, wgt[j]);
            else       mfma_a(accE, am, wgt[j]);
        }
        if (sRole) {
            #pragma unroll
            for (int j = 0; j < 4; ++j) {
                bf16x8 ax = *(const bf16x8*)&xlds[l15][j * 32 + koff];
                if (j & 1) mfma_a(accO, ax, wgt[32 + j]);
                else       mfma_a(accE, ax, wgt[32 + j]);
            }
        }
    }

    for (int t = 0; t < TLEN; ++t) {
        __syncthreads();                          // bar0: prior LDS reads done

        // (a/b) finish state, stage own slices
        ACC_GUARD(accE, accO);
        f32x4 va = accE + accO;
        if (sRole) {
            const float addc = (t == 0) ? b1r : cbr;
            #pragma unroll
            for (int r = 0; r < 4; ++r)
                flds[4 * l4 + r][c0] = (__bf16)tanhf(va[r] + addc);
        } else {
            const float addu = (t == 0) ? 0.f : cur;
            #pragma unroll
            for (int r = 0; r < 4; ++r)
                ulds[4 * l4 + r][c0] = (__bf16)(va[r] + addu);
        }
        __syncthreads();                          // bar1: own slices staged

        // (c) export (u,f) own blocks: 1 u64/thread, coalesced
        const size_t bufbase = (size_t)((t & 1) * NGRP + g) * (2 * BC * MDIM);
        {
            int mat = tid >> 8;                   // 0=u, 1=f
            int rr = (tid & 255) >> 4, c4 = (tid & 15) << 2;
            const __bf16* src = mat ? &flds[rr][64 * p + c4] : &ulds[rr][64 * p + c4];
            u64 v = *(const u64*)src;
            __hip_atomic_store((u64*)(buf + bufbase + (size_t)mat * (BC * MDIM)
                                      + rr * MDIM + 64 * p + c4),
                               v, __ATOMIC_RELAXED, __HIP_MEMORY_SCOPE_AGENT);
        }
        asm volatile("s_waitcnt vmcnt(0)" ::: "memory");
        __syncthreads();                          // bar2: exports drained
        if (tid == 0)
            __hip_atomic_store(&flags[p], (u32)t + 1u,
                               __ATOMIC_RELAXED, __HIP_MEMORY_SCOPE_AGENT);

        // (d) stage x_{t+1} into xlds (consumed at (f) below, after bar3)
        if (tid < 256 && t + 1 < TLEN) {
            int rr = tid >> 4, c8 = (tid & 15) << 3;
            const float* xs = &x[((size_t)(row0 + rr) * TLEN + (t + 1)) * IDIM + c8];
            float4 v0 = ((const float4*)xs)[0], v1 = ((const float4*)xs)[1];
            *(bf16x8*)&xlds[rr][c8] =
                bf16x8{(__bf16)v0.x, (__bf16)v0.y, (__bf16)v0.z, (__bf16)v0.w,
                       (__bf16)v1.x, (__bf16)v1.y, (__bf16)v1.z, (__bf16)v1.w};
        }
        poll_flags(flags, (u32)t + 1u, lane, alive);

        // (e) gather full (u_t, f_t): 4 x 16B/thread, coalesced
        #pragma unroll
        for (int i = 0; i < 4; ++i) {
            int c = tid + 512 * i;                // 2048 chunks of 8 elems
            int mat = c >> 10, rem = c & 1023;
            int row = rem >> 6, col8 = (rem & 63) << 3;
            const __bf16* src = buf + bufbase + (size_t)mat * (BC * MDIM)
                              + row * MDIM + col8;
            u64 lo = __hip_atomic_load((const u64*)src,     __ATOMIC_RELAXED, __HIP_MEMORY_SCOPE_AGENT);
            u64 hi = __hip_atomic_load((const u64*)src + 1, __ATOMIC_RELAXED, __HIP_MEMORY_SCOPE_AGENT);
            union { u64 q[2]; bf16x8 v; } uu; uu.q[0] = lo; uu.q[1] = hi;
            if (mat) *(bf16x8*)&flds[row][col8] = uu.v;
            else     *(bf16x8*)&ulds[row][col8] = uu.v;
        }
        __syncthreads();                          // bar3: ulds/flds = epoch t

        if (t == TLEN - 1) break;

        // (f) next state: s' = u@W2F + f@C + x@WI ; u' = u@W2M + f@D
        {
            bf16x8 a0 = *(const bf16x8*)&ulds[l15][0 * 32 + koff];
            bf16x8 a1 = *(const bf16x8*)&ulds[l15][1 * 32 + koff];
            mfma_z(accE, a0, wgt[0]);  mfma_z(accO, a1, wgt[1]);
            #pragma unroll
            for (int j = 2; j < 16; ++j) {
                bf16x8 am = *(const bf16x8*)&ulds[l15][j * 32 + koff];
                if (j & 1) mfma_a(accO, am, wgt[j]);
                else       mfma_a(accE, am, wgt[j]);
            }
            #pragma unroll
            for (int j = 0; j < 16; ++j) {
                bf16x8 af = *(const bf16x8*)&flds[l15][j * 32 + koff];
                if (j & 1) mfma_a(accO, af, wgt[16 + j]);
                else       mfma_a(accE, af, wgt[16 + j]);
            }
            if (sRole) {
                #pragma unroll
                for (int j = 0; j < 4; ++j) {
                    bf16x8 ax = *(const bf16x8*)&xlds[l15][j * 32 + koff];
                    if (j & 1) mfma_a(accO, ax, wgt[32 + j]);
                    else       mfma_a(accE, ax, wgt[32 + j]);
                }
            }
        }
    }

    // ---- epilogue (p==0): m_T = u + f@WF2^T + b23; out = m_T@WO^T + bout ----
    if (p == 0) {
        f32x4 ma[4];
        #pragma unroll
        for (int nt = 0; nt < 4; ++nt) {
            int ct = 64 * w + 16 * nt + l15;
            f32x4 acc = {0, 0, 0, 0};
            #pragma unroll
            for (int j = 0; j < 16; ++j) {
                bf16x8 af = *(const bf16x8*)&flds[l15][j * 32 + koff];
                bf16x8 bw = *(const bf16x8*)&WF2[(size_t)ct * FDIM + j * 32 + koff];
                acc = mfma16(af, bw, acc);
            }
            ma[nt] = acc;
        }
        #pragma unroll
        for (int nt = 0; nt < 4; ++nt) {
            int ct = 64 * w + 16 * nt + l15;
            #pragma unroll
            for (int r = 0; r < 4; ++r) {
                float mv = ma[nt][r] + (float)ulds[4 * l4 + r][ct] + b23[ct];
                ulds[4 * l4 + r][ct] = (__bf16)mv;    // own cols only: no race
            }
        }
        __syncthreads();
        const int oc = 16 * w + l15;
        const __bf16* ro = WO + (size_t)oc * MDIM;
        f32x4 oe = {0, 0, 0, 0}, oo = {0, 0, 0, 0};
        #pragma unroll
        for (int j = 0; j < 16; ++j) {
            bf16x8 am = *(const bf16x8*)&ulds[l15][j * 32 + koff];
            bf16x8 bw = *(const bf16x8*)&ro[j * 32 + koff];
            if (j & 1) oo = mfma16(am, bw, oo); else oe = mfma16(am, bw, oe);
        }
        f32x4 oa = oe + oo;
        const float bo = bout[oc];
        #pragma unroll
        for (int r = 0; r < 4; ++r)
            out[(size_t)(row0 + 4 * l4 + r) * ODIM + oc] = oa[r] + bo;
    }
}

extern "C" void kernel_launch(void* const* d_in, const int* in_sizes, int n_in,
                              void* d_out, int out_size, void* d_ws, size_t ws_size,
                              hipStream_t stream)
{
    const float* x    = (const float*)d_in[0];
    const float* m0   = (const float*)d_in[1];
    const float* Wi2f = (const float*)d_in[2];
    const float* bi2f = (const float*)d_in[3];
    const float* Wm2f = (const float*)d_in[4];
    const float* bm2f = (const float*)d_in[5];
    const float* Wf2m = (const float*)d_in[6];
    const float* bf2m = (const float*)d_in[7];
    const float* Wm2m = (const float*)d_in[8];
    const float* bm2m = (const float*)d_in[9];
    const float* Wout = (const float*)d_in[10];
    const float* bout = (const float*)d_in[11];

    char* ws = (char*)d_ws;
    __bf16* WI  = (__bf16*)(ws + WS_WI);
    __bf16* W2F = (__bf16*)(ws + WS_W2F);
    __bf16* W2M = (__bf16*)(ws + WS_W2M);
    __bf16* WF2 = (__bf16*)(ws + WS_WF2);
    __bf16* WO  = (__bf16*)(ws + WS_WO);
    __bf16* Cm  = (__bf16*)(ws + WS_C);
    __bf16* Dm  = (__bf16*)(ws + WS_D);
    float*  b1  = (float*)(ws + WS_B1);
    float*  b23 = (float*)(ws + WS_B23);
    float*  cb  = (float*)(ws + WS_CB);
    float*  cu  = (float*)(ws + WS_CU);
    u32*    flg = (u32*)(ws + WS_FLG);
    __bf16* buf = (__bf16*)(ws + WS_BUF);

    const int prep1_total = N_WI + N_W2F + N_W2M + N_WF2 + N_WO
                          + FDIM + MDIM + NGRP * 64;
    lmn_prep1<<<(prep1_total + 255) / 256, 256, 0, stream>>>(
        Wi2f, Wm2f, Wm2m, Wf2m, Wout, bi2f, bm2f, bf2m, bm2m,
        WI, W2F, W2M, WF2, WO, b1, b23, flg);

    lmn_prep2<<<2052, 256, 0, stream>>>(Wm2f, Wm2m, Wf2m, b1, b23, Cm, Dm, cb, cu);

    lmn_scan<<<NGRP * NCU, 512, 0, stream>>>(
        x, m0, WI, W2F, W2M, Cm, Dm, WF2, WO,
        b1, cb, cu, b23, bout, flg, buf, (float*)d_out);
}